// Round 12
// baseline (736.759 us; speedup 1.0000x reference)
//
#include <hip/hip_runtime.h>
#include <math.h>

typedef unsigned short ushort_t;
typedef __attribute__((ext_vector_type(8))) short short8;
typedef __attribute__((ext_vector_type(4))) short short4_t;
typedef __attribute__((ext_vector_type(4))) float f32x4;

#define MFMA_BF16(a,b,c) __builtin_amdgcn_mfma_f32_16x16x32_bf16((a),(b),(c),0,0,0)

__device__ __forceinline__ ushort_t f2bf(float f){
  union { float f; unsigned int i; } v; v.f = f;
  unsigned int r = v.i + 0x7fffu + ((v.i >> 16) & 1u);
  return (ushort_t)(r >> 16);
}
// branch-free inline gelu (A&S 7.1.26 erf, |err|<1.5e-7) — no libm call
__device__ __forceinline__ float gelu_f(float x){
  float z  = x * 0.70710678118654752f;
  float az = fabsf(z);
  float t  = __builtin_amdgcn_rcpf(1.0f + 0.3275911f * az);
  float p  = t * (0.254829592f + t * (-0.284496736f + t * (1.421413741f
             + t * (-1.453152027f + t * 1.061405429f))));
  float e  = __expf(-az * az);
  float er = 1.0f - p * e;
  er = copysignf(er, z);
  return 0.5f * x * (1.0f + er);
}
__device__ __forceinline__ short8 cvt8(const float* __restrict__ p){
  f32x4 a = *(const f32x4*)p;
  f32x4 b = *(const f32x4*)(p + 4);
  short8 t;
#pragma unroll
  for (int j = 0; j < 4; ++j) { t[j] = (short)f2bf(a[j]); t[4 + j] = (short)f2bf(b[j]); }
  return t;
}

// ---------------------------------------------------------------- prep: CSR
__global__ void k_prep(const int* __restrict__ e0, const int* __restrict__ pos,
                       int m, int* __restrict__ startp, int* __restrict__ degp){
  int i = blockIdx.x * 256 + threadIdx.x;
  if (i >= m) return;
  int s = e0[i];
  if (pos[i] == 0) startp[s] = i;
  if (i == m - 1 || e0[i + 1] != s) degp[s] = pos[i] + 1;
}

// ---------------------------------------------------------------- weights f32 -> bf16 (once)
__global__ void k_wcvt(const float* __restrict__ Wc, const float* __restrict__ Wq,
                       const float* __restrict__ Wk, const float* __restrict__ Wv,
                       const float* __restrict__ Wo, ushort_t* __restrict__ wb){
  int i = blockIdx.x * 256 + threadIdx.x;
  if (i >= 5 * 65536) return;
  int s = i >> 16, off = i & 65535;
  const float* src = (s == 0) ? Wc : (s == 1) ? Wq : (s == 2) ? Wk : (s == 3) ? Wv : Wo;
  wb[i] = f2bf(src[off]);
}

// 32-row x 64-col (per-wave) x 256-k GEMM core
template<bool WB>
__device__ __forceinline__ void gemm_tile(const ushort_t* __restrict__ sA,
    const ushort_t* __restrict__ wp, const float* __restrict__ wf,
    int colbase, int li, int g, f32x4 acc[2][4])
{
#pragma unroll
  for (int ks = 0; ks < 8; ++ks) {
    short8 bf[4];
#pragma unroll
    for (int nf = 0; nf < 4; ++nf) {
      int off = (colbase + nf * 16 + li) * 256 + ks * 32 + g * 8;
      bf[nf] = WB ? *(const short8*)(wp + off) : cvt8(wf + off);
    }
    short8 af[2];
#pragma unroll
    for (int mt = 0; mt < 2; ++mt)
      af[mt] = *(const short8*)&sA[(mt * 16 + li) * 264 + ks * 32 + g * 8];
#pragma unroll
    for (int nf = 0; nf < 4; ++nf)
#pragma unroll
      for (int mt = 0; mt < 2; ++mt)
        acc[mt][nf] = MFMA_BF16(af[mt], bf[nf], acc[mt][nf]);
  }
}

// ================================================================ FUSED
// r11 body; launch_bounds(256,1): hipcc's 2nd arg costs 2x the intended VGPR
// budget (observed: (256,2)->104, (256,3)->84=512/6, (256,4)->64=512/8).
// (256,1) => budget 256: allocator free (~104-140, no spill), loads hoistable;
// HW occupancy then set by usage: VGPR<=128 & LDS 37.4KB -> 4 blocks/CU.
template<bool WB>
__global__ __launch_bounds__(256, 1) void k_fused4(
    const float* __restrict__ x,
    const ushort_t* __restrict__ wb,
    const float* __restrict__ Wcf, const float* __restrict__ bc,
    const float* __restrict__ Wqf, const float* __restrict__ bq,
    const float* __restrict__ Wkf, const float* __restrict__ bk,
    const float* __restrict__ Wvf, const float* __restrict__ bv,
    const float* __restrict__ Wof, const float* __restrict__ bo,
    const int* __restrict__ e1,
    const int* __restrict__ startp, const int* __restrict__ degp,
    float* __restrict__ dout, int n)
{
  __shared__ __align__(16) ushort_t sX[32 * 264];   // ex tile; attn-out overlays later
  __shared__ __align__(16) ushort_t sS[4 * 2560];   // per-wave scratch; x-stage overlays in phases 0-1

  const int node = blockIdx.x;
  const int st = startp[node], dg = degp[node];
  if (dg <= 0) return;
  const int tid = threadIdx.x;
  const int w = tid >> 6, lane = tid & 63;
  const int g = lane >> 4, li = lane & 15;
  const int colbase = w * 64;
  ushort_t* myS = &sS[w * 2560];

  // -------- phase 0: stage A rows (bf16): dst rows [32][136] + src row [128]
  {
    int r = tid >> 3, seg = tid & 7;
    int dn = e1[st + min(r, dg - 1)];
    const float* s = x + (size_t)dn * 128 + seg * 16;
    *(short8*)&sS[r * 136 + seg * 16]     = cvt8(s);
    *(short8*)&sS[r * 136 + seg * 16 + 8] = cvt8(s + 8);
    if (tid < 16)
      *(short8*)&sS[4352 + tid * 8] = cvt8(x + (size_t)node * 128 + tid * 8);
  }
  __syncthreads();

  // -------- phase 1: ex = gelu([x_src | x_dst] Wc^T + bc) -> sX
  {
    f32x4 acc[2][4];
#pragma unroll
    for (int a = 0; a < 2; ++a)
#pragma unroll
      for (int b = 0; b < 4; ++b) acc[a][b] = (f32x4){0.f,0.f,0.f,0.f};
#pragma unroll
    for (int ks = 0; ks < 8; ++ks) {
      short8 bf[4];
#pragma unroll
      for (int nf = 0; nf < 4; ++nf) {
        int off = (colbase + nf * 16 + li) * 256 + ks * 32 + g * 8;
        bf[nf] = WB ? *(const short8*)(wb + off) : cvt8(Wcf + off);
      }
      short8 af[2];
      if (ks < 4) {
        short8 t = *(const short8*)&sS[4352 + ks * 32 + g * 8];
        af[0] = t; af[1] = t;
      } else {
#pragma unroll
        for (int mt = 0; mt < 2; ++mt)
          af[mt] = *(const short8*)&sS[(mt * 16 + li) * 136 + (ks - 4) * 32 + g * 8];
      }
#pragma unroll
      for (int nf = 0; nf < 4; ++nf)
#pragma unroll
        for (int mt = 0; mt < 2; ++mt)
          acc[mt][nf] = MFMA_BF16(af[mt], bf[nf], acc[mt][nf]);
    }
#pragma unroll
    for (int nf = 0; nf < 4; ++nf) {
      int col = colbase + nf * 16 + li;
      float b = bc[col];
#pragma unroll
      for (int mt = 0; mt < 2; ++mt)
#pragma unroll
        for (int r = 0; r < 4; ++r)
          sX[(mt * 16 + g * 4 + r) * 264 + col] = f2bf(gelu_f(acc[mt][nf][r] + b));
    }
  }
  __syncthreads();   // sX complete; x-stage dead -> scratch usable

  // -------- phase 2: Q, K, V (wave-private transposes through myS; frags -> registers)
  short8 qa[2][2], kbf[2][2], vbf[4];
  { // Q
    f32x4 acc[2][4];
#pragma unroll
    for (int a = 0; a < 2; ++a)
#pragma unroll
      for (int b = 0; b < 4; ++b) acc[a][b] = (f32x4){0.f,0.f,0.f,0.f};
    gemm_tile<WB>(sX, wb + 65536, Wqf, colbase, li, g, acc);
#pragma unroll
    for (int nf = 0; nf < 4; ++nf) {
      float b = bq[colbase + nf * 16 + li];
#pragma unroll
      for (int mt = 0; mt < 2; ++mt)
#pragma unroll
        for (int r = 0; r < 4; ++r)
          myS[(mt * 16 + g * 4 + r) * 72 + nf * 16 + li] = f2bf((acc[mt][nf][r] + b) * 0.125f);
    }
#pragma unroll
    for (int mt = 0; mt < 2; ++mt)
#pragma unroll
      for (int k2 = 0; k2 < 2; ++k2)
        qa[mt][k2] = *(const short8*)&myS[(mt * 16 + li) * 72 + k2 * 32 + g * 8];
  }
  { // K
    f32x4 acc[2][4];
#pragma unroll
    for (int a = 0; a < 2; ++a)
#pragma unroll
      for (int b = 0; b < 4; ++b) acc[a][b] = (f32x4){0.f,0.f,0.f,0.f};
    gemm_tile<WB>(sX, wb + 2 * 65536, Wkf, colbase, li, g, acc);
#pragma unroll
    for (int nf = 0; nf < 4; ++nf) {
      float b = bk[colbase + nf * 16 + li];
#pragma unroll
      for (int mt = 0; mt < 2; ++mt)
#pragma unroll
        for (int r = 0; r < 4; ++r)
          myS[(mt * 16 + g * 4 + r) * 72 + nf * 16 + li] = f2bf(acc[mt][nf][r] + b);
    }
#pragma unroll
    for (int nt = 0; nt < 2; ++nt)
#pragma unroll
      for (int k2 = 0; k2 < 2; ++k2)
        kbf[nt][k2] = *(const short8*)&myS[(nt * 16 + li) * 72 + k2 * 32 + g * 8];
  }
  { // V
    f32x4 acc[2][4];
#pragma unroll
    for (int a = 0; a < 2; ++a)
#pragma unroll
      for (int b = 0; b < 4; ++b) acc[a][b] = (f32x4){0.f,0.f,0.f,0.f};
    gemm_tile<WB>(sX, wb + 3 * 65536, Wvf, colbase, li, g, acc);
#pragma unroll
    for (int nf = 0; nf < 4; ++nf) {
      float b = bv[colbase + nf * 16 + li];
#pragma unroll
      for (int mt = 0; mt < 2; ++mt)
#pragma unroll
        for (int r = 0; r < 4; ++r)
          myS[(nf * 16 + li) * 40 + mt * 16 + g * 4 + r] = f2bf(acc[mt][nf][r] + b);
    }
#pragma unroll
    for (int nf = 0; nf < 4; ++nf)
      vbf[nf] = *(const short8*)&myS[(nf * 16 + li) * 40 + g * 8];
  }

  // -------- phase 3: attention (head = wave), all operands in registers
  f32x4 o[2][4];
  {
    f32x4 sc[2][2];
#pragma unroll
    for (int a = 0; a < 2; ++a)
#pragma unroll
      for (int b = 0; b < 2; ++b) sc[a][b] = (f32x4){0.f,0.f,0.f,0.f};
#pragma unroll
    for (int k2 = 0; k2 < 2; ++k2)
#pragma unroll
      for (int mt = 0; mt < 2; ++mt)
#pragma unroll
        for (int nt = 0; nt < 2; ++nt)
          sc[mt][nt] = MFMA_BF16(qa[mt][k2], kbf[nt][k2], sc[mt][nt]);
#pragma unroll
    for (int mt = 0; mt < 2; ++mt) {
#pragma unroll
      for (int nt = 0; nt < 2; ++nt) {
        bool ok = (nt * 16 + li) < dg;
#pragma unroll
        for (int r = 0; r < 4; ++r) sc[mt][nt][r] = ok ? sc[mt][nt][r] : -1e30f;
      }
#pragma unroll
      for (int r = 0; r < 4; ++r) {
        float mx = fmaxf(sc[mt][0][r], sc[mt][1][r]);
#pragma unroll
        for (int d = 1; d < 16; d <<= 1) mx = fmaxf(mx, __shfl_xor(mx, d));
        float s0 = __expf(sc[mt][0][r] - mx);
        float s1 = __expf(sc[mt][1][r] - mx);
        float sum = s0 + s1;
#pragma unroll
        for (int d = 1; d < 16; d <<= 1) sum += __shfl_xor(sum, d);
        float inv = __builtin_amdgcn_rcpf(sum);
        sc[mt][0][r] = s0 * inv;
        sc[mt][1][r] = s1 * inv;
      }
    }
#pragma unroll
    for (int mt = 0; mt < 2; ++mt)
#pragma unroll
      for (int nt = 0; nt < 2; ++nt)
#pragma unroll
        for (int r = 0; r < 4; ++r)
          myS[(mt * 16 + g * 4 + r) * 36 + nt * 16 + li] = f2bf(sc[mt][nt][r]);
    short8 pa[2];
#pragma unroll
    for (int mt = 0; mt < 2; ++mt)
      pa[mt] = *(const short8*)&myS[(mt * 16 + li) * 36 + g * 8];
#pragma unroll
    for (int a = 0; a < 2; ++a)
#pragma unroll
      for (int b = 0; b < 4; ++b) o[a][b] = (f32x4){0.f,0.f,0.f,0.f};
#pragma unroll
    for (int nf = 0; nf < 4; ++nf)
#pragma unroll
      for (int mt = 0; mt < 2; ++mt) o[mt][nf] = MFMA_BF16(pa[mt], vbf[nf], o[mt][nf]);
  }
  __syncthreads();   // all phase-2 sX reads done -> safe to overlay
#pragma unroll
  for (int mt = 0; mt < 2; ++mt)
#pragma unroll
    for (int nf = 0; nf < 4; ++nf)
#pragma unroll
      for (int r = 0; r < 4; ++r)
        sX[(mt * 16 + g * 4 + r) * 264 + colbase + nf * 16 + li] = f2bf(o[mt][nf][r]);
  __syncthreads();   // attn-out complete

  // -------- phase 4: Wo GEMM + gelu + group softmax over logits + scatter
  {
    f32x4 acc[2][4];
#pragma unroll
    for (int a = 0; a < 2; ++a)
#pragma unroll
      for (int b = 0; b < 4; ++b) acc[a][b] = (f32x4){0.f,0.f,0.f,0.f};
    gemm_tile<WB>(sX, wb + 4 * 65536, Wof, colbase, li, g, acc);
#pragma unroll
    for (int nf = 0; nf < 4; ++nf) {
      float b = bo[colbase + nf * 16 + li];
#pragma unroll
      for (int mt = 0; mt < 2; ++mt)
#pragma unroll
        for (int r = 0; r < 4; ++r) acc[mt][nf][r] = gelu_f(acc[mt][nf][r] + b);
    }
    float lp[2][4];
#pragma unroll
    for (int mt = 0; mt < 2; ++mt)
#pragma unroll
      for (int r = 0; r < 4; ++r) lp[mt][r] = acc[mt][2][r] + acc[mt][3][r];
#pragma unroll
    for (int d = 1; d < 16; d <<= 1)
#pragma unroll
      for (int mt = 0; mt < 2; ++mt)
#pragma unroll
        for (int r = 0; r < 4; ++r) lp[mt][r] += __shfl_xor(lp[mt][r], d);
    float ml[2][4], mx = -1e30f;
#pragma unroll
    for (int mt = 0; mt < 2; ++mt)
#pragma unroll
      for (int r = 0; r < 4; ++r) {
        int rin = mt * 16 + g * 4 + r;
        ml[mt][r] = (rin < dg) ? lp[mt][r] * (1.f / 32.f) : -1e30f;
        mx = fmaxf(mx, ml[mt][r]);
      }
    mx = fmaxf(mx, __shfl_xor(mx, 16));
    mx = fmaxf(mx, __shfl_xor(mx, 32));
    float ee[2][4], ss = 0.f;
#pragma unroll
    for (int mt = 0; mt < 2; ++mt)
#pragma unroll
      for (int r = 0; r < 4; ++r) {
        int rin = mt * 16 + g * 4 + r;
        ee[mt][r] = (rin < dg) ? __expf(ml[mt][r] - mx) : 0.f;
        ss += ee[mt][r];
      }
    ss += __shfl_xor(ss, 16);
    ss += __shfl_xor(ss, 32);
    float inv = __builtin_amdgcn_rcpf(ss);
#pragma unroll
    for (int mt = 0; mt < 2; ++mt)
#pragma unroll
      for (int r = 0; r < 4; ++r) {
        int rin = mt * 16 + g * 4 + r;
        if (rin < dg) {
          int eo = e1[st + rin];
          float a = ee[mt][r] * inv;
          atomicAdd(&dout[(size_t)eo * 128 + w * 32 + li],      acc[mt][0][r] * a);
          atomicAdd(&dout[(size_t)eo * 128 + w * 32 + 16 + li], acc[mt][1][r] * a);
        }
      }
  }
}

// ---------------------------------------------------------------- launch
extern "C" void kernel_launch(void* const* d_in, const int* in_sizes, int n_in,
                              void* d_out, int out_size, void* d_ws, size_t ws_size,
                              hipStream_t stream) {
  (void)n_in;
  const float* x  = (const float*)d_in[0];
  const float* Wc = (const float*)d_in[1];
  const float* bc = (const float*)d_in[2];
  const float* Wq = (const float*)d_in[3];
  const float* bq = (const float*)d_in[4];
  const float* Wk = (const float*)d_in[5];
  const float* bk = (const float*)d_in[6];
  const float* Wv = (const float*)d_in[7];
  const float* bv = (const float*)d_in[8];
  const float* Wo = (const float*)d_in[9];
  const float* bo = (const float*)d_in[10];
  const int* e0  = (const int*)d_in[11];
  const int* e1  = (const int*)d_in[12];
  const int* pos = (const int*)d_in[13];
  const int m = in_sizes[11];
  const int n = in_sizes[0] / 128;

  const size_t WBYTES = (size_t)5 * 65536 * sizeof(ushort_t);   // 640 KB
  const bool use_wb = ws_size >= WBYTES + (size_t)n * 2 * sizeof(int);

  ushort_t* wb = (ushort_t*)d_ws;
  int* startp = use_wb ? (int*)((char*)d_ws + WBYTES) : (int*)d_ws;
  int* degp = startp + n;

  hipMemsetAsync(d_out, 0, (size_t)out_size * sizeof(float), stream);
  hipMemsetAsync(startp, 0, (size_t)n * 2 * sizeof(int), stream);

  k_prep<<<(m + 255) / 256, 256, 0, stream>>>(e0, pos, m, startp, degp);
  if (use_wb) {
    k_wcvt<<<(5 * 65536 + 255) / 256, 256, 0, stream>>>(Wc, Wq, Wk, Wv, Wo, wb);
    k_fused4<true><<<n, 256, 0, stream>>>(x, wb, Wc, bc, Wq, bq, Wk, bk, Wv, bv, Wo, bo,
                                          e1, startp, degp, (float*)d_out, n);
  } else {
    k_fused4<false><<<n, 256, 0, stream>>>(x, nullptr, Wc, bc, Wq, bq, Wk, bk, Wv, bv, Wo, bo,
                                           e1, startp, degp, (float*)d_out, n);
  }
}

// Round 13
// 510.746 us; speedup vs baseline: 1.4425x; 1.4425x over previous
//
#include <hip/hip_runtime.h>
#include <math.h>

typedef unsigned short ushort_t;
typedef __attribute__((ext_vector_type(8))) short short8;
typedef __attribute__((ext_vector_type(4))) short short4_t;
typedef __attribute__((ext_vector_type(4))) float f32x4;

#define MFMA_BF16(a,b,c) __builtin_amdgcn_mfma_f32_16x16x32_bf16((a),(b),(c),0,0,0)

__device__ __forceinline__ ushort_t f2bf(float f){
  union { float f; unsigned int i; } v; v.f = f;
  unsigned int r = v.i + 0x7fffu + ((v.i >> 16) & 1u);
  return (ushort_t)(r >> 16);
}
// branch-free inline gelu (A&S 7.1.26 erf, |err|<1.5e-7) — no libm call (r11 win)
__device__ __forceinline__ float gelu_f(float x){
  float z  = x * 0.70710678118654752f;
  float az = fabsf(z);
  float t  = __builtin_amdgcn_rcpf(1.0f + 0.3275911f * az);
  float p  = t * (0.254829592f + t * (-0.284496736f + t * (1.421413741f
             + t * (-1.453152027f + t * 1.061405429f))));
  float e  = __expf(-az * az);
  float er = 1.0f - p * e;
  er = copysignf(er, z);
  return 0.5f * x * (1.0f + er);
}
__device__ __forceinline__ short8 cvt8(const float* __restrict__ p){
  f32x4 a = *(const f32x4*)p;
  f32x4 b = *(const f32x4*)(p + 4);
  short8 t;
#pragma unroll
  for (int j = 0; j < 4; ++j) { t[j] = (short)f2bf(a[j]); t[4 + j] = (short)f2bf(b[j]); }
  return t;
}

// ---------------------------------------------------------------- prep: CSR
__global__ void k_prep(const int* __restrict__ e0, const int* __restrict__ pos,
                       int m, int* __restrict__ startp, int* __restrict__ degp){
  int i = blockIdx.x * 256 + threadIdx.x;
  if (i >= m) return;
  int s = e0[i];
  if (pos[i] == 0) startp[s] = i;
  if (i == m - 1 || e0[i + 1] != s) degp[s] = pos[i] + 1;
}

// ---------------------------------------------------------------- weights f32 -> bf16 (once)
__global__ void k_wcvt(const float* __restrict__ Wc, const float* __restrict__ Wq,
                       const float* __restrict__ Wk, const float* __restrict__ Wv,
                       const float* __restrict__ Wo, ushort_t* __restrict__ wb){
  int i = blockIdx.x * 256 + threadIdx.x;
  if (i >= 5 * 65536) return;
  int s = i >> 16, off = i & 65535;
  const float* src = (s == 0) ? Wc : (s == 1) ? Wq : (s == 2) ? Wk : (s == 3) ? Wv : Wo;
  wb[i] = f2bf(src[off]);
}

// ================================================================ FUSED (2 nodes/block)
// r10 structure, de-confounded: inline gelu (r11) + launch_bounds(256,1) so the
// allocator is unconstrained (hipcc 2nd-arg law: budget=512/(2*arg); (256,3)
// gave 84 VGPR -> r10 spilled 340MB). Fewer block-slots (4000 vs 8000) halves
// the number of serialized weight-load chains; each load feeds 16 MFMAs.
template<bool WB>
__global__ __launch_bounds__(256, 1) void k_fused5(
    const float* __restrict__ x,
    const ushort_t* __restrict__ wb,
    const float* __restrict__ Wcf, const float* __restrict__ bc,
    const float* __restrict__ Wqf, const float* __restrict__ bq,
    const float* __restrict__ Wkf, const float* __restrict__ bk,
    const float* __restrict__ Wvf, const float* __restrict__ bv,
    const float* __restrict__ Wof, const float* __restrict__ bo,
    const int* __restrict__ e1,
    const int* __restrict__ startp, const int* __restrict__ degp,
    float* __restrict__ dout, int n)
{
  __shared__ __align__(16) ushort_t sX[64 * 264];  // ex tile [64][264]; x-stage overlays (dst [64][136] + src 2x[128])
  __shared__ __align__(16) ushort_t sS[4 * 1440];  // per-wave scratch: QK half [16][72] / V half [32][40] / P [32][36]

  const int tid = threadIdx.x;
  const int w = tid >> 6, lane = tid & 63;
  const int g = lane >> 4, li = lane & 15;
  const int colbase = w * 64;
  ushort_t* myS = &sS[w * 1440];

  int st2[2], dg2[2], nodev[2];
#pragma unroll
  for (int nd = 0; nd < 2; ++nd) {
    int node = blockIdx.x * 2 + nd;
    nodev[nd] = min(node, n - 1);
    if (node < n) { st2[nd] = startp[node]; dg2[nd] = degp[node]; }
    else { st2[nd] = 0; dg2[nd] = 0; }
  }
  if (dg2[0] <= 0 && dg2[1] <= 0) return;

  // -------- phase 0: stage x rows (bf16) into sX region: dst [64][136] + src at 8704
  {
    int r = tid >> 2, seg = tid & 3;               // 64 rows x 4 threads (32 f32 each)
    int nd0 = r >> 5, rin0 = r & 31;
    int dn = (dg2[nd0] > 0) ? e1[st2[nd0] + min(rin0, dg2[nd0] - 1)] : 0;
    const float* s = x + (size_t)dn * 128 + seg * 32;
    ushort_t* xd = &sX[r * 136 + seg * 32];
    *(short8*)(xd)      = cvt8(s);      *(short8*)(xd + 8)  = cvt8(s + 8);
    *(short8*)(xd + 16) = cvt8(s + 16); *(short8*)(xd + 24) = cvt8(s + 24);
    if (tid < 32) {
      int nd = tid >> 4, j = tid & 15;
      *(short8*)&sX[8704 + nd * 128 + j * 8] = cvt8(x + (size_t)nodev[nd] * 128 + j * 8);
    }
  }
  __syncthreads();   // (1) x-stage ready

  // -------- phase 1: ex = gelu([x_src | x_dst] Wc^T + bc); acc in regs, write after barrier
  {
    f32x4 acc[4][4];
#pragma unroll
    for (int a = 0; a < 4; ++a)
#pragma unroll
      for (int b = 0; b < 4; ++b) acc[a][b] = (f32x4){0.f,0.f,0.f,0.f};
#pragma unroll
    for (int ks = 0; ks < 8; ++ks) {
      short8 bf[4];
#pragma unroll
      for (int nf = 0; nf < 4; ++nf) {
        int off = (colbase + nf * 16 + li) * 256 + ks * 32 + g * 8;
        bf[nf] = WB ? *(const short8*)(wb + off) : cvt8(Wcf + off);
      }
      short8 af[4];
      if (ks < 4) {
        int k0 = ks * 32 + g * 8;
#pragma unroll
        for (int mt = 0; mt < 4; ++mt)
          af[mt] = *(const short8*)&sX[8704 + (mt >> 1) * 128 + k0];
      } else {
#pragma unroll
        for (int mt = 0; mt < 4; ++mt)
          af[mt] = *(const short8*)&sX[(mt * 16 + li) * 136 + (ks - 4) * 32 + g * 8];
      }
#pragma unroll
      for (int nf = 0; nf < 4; ++nf)
#pragma unroll
        for (int mt = 0; mt < 4; ++mt)
          acc[mt][nf] = MFMA_BF16(af[mt], bf[nf], acc[mt][nf]);
    }
    __syncthreads();   // (2) all x-stage reads done -> sX reusable
#pragma unroll
    for (int nf = 0; nf < 4; ++nf) {
      int col = colbase + nf * 16 + li;
      float b = bc[col];
#pragma unroll
      for (int mt = 0; mt < 4; ++mt)
#pragma unroll
        for (int r = 0; r < 4; ++r)
          sX[(mt * 16 + g * 4 + r) * 264 + col] = f2bf(gelu_f(acc[mt][nf][r] + b));
    }
  }
  __syncthreads();   // (3) ex complete

  // -------- phase 2a: Q GEMM -> qa regs (A-frags per node)
  short8 qa[2][2][2], kbf[2][2][2];
  {
    f32x4 acc[4][4];
#pragma unroll
    for (int a = 0; a < 4; ++a)
#pragma unroll
      for (int b = 0; b < 4; ++b) acc[a][b] = (f32x4){0.f,0.f,0.f,0.f};
#pragma unroll
    for (int ks = 0; ks < 8; ++ks) {
      short8 bf[4];
#pragma unroll
      for (int nf = 0; nf < 4; ++nf) {
        int off = (colbase + nf * 16 + li) * 256 + ks * 32 + g * 8;
        bf[nf] = WB ? *(const short8*)(wb + 65536 + off) : cvt8(Wqf + off);
      }
      short8 af[4];
#pragma unroll
      for (int mt = 0; mt < 4; ++mt)
        af[mt] = *(const short8*)&sX[(mt * 16 + li) * 264 + ks * 32 + g * 8];
#pragma unroll
      for (int nf = 0; nf < 4; ++nf)
#pragma unroll
        for (int mt = 0; mt < 4; ++mt)
          acc[mt][nf] = MFMA_BF16(af[mt], bf[nf], acc[mt][nf]);
    }
    float bqv[4];
#pragma unroll
    for (int nf = 0; nf < 4; ++nf) bqv[nf] = bq[colbase + nf * 16 + li];
#pragma unroll
    for (int nd = 0; nd < 2; ++nd)
#pragma unroll
      for (int t = 0; t < 2; ++t) {
        int mt = nd * 2 + t;
#pragma unroll
        for (int nf = 0; nf < 4; ++nf)
#pragma unroll
          for (int r = 0; r < 4; ++r)
            myS[(g * 4 + r) * 72 + nf * 16 + li] = f2bf((acc[mt][nf][r] + bqv[nf]) * 0.125f);
#pragma unroll
        for (int k2 = 0; k2 < 2; ++k2)
          qa[nd][t][k2] = *(const short8*)&myS[li * 72 + k2 * 32 + g * 8];
      }
  }
  // -------- phase 2b: K GEMM -> kbf regs (B-frags per node)
  {
    f32x4 acc[4][4];
#pragma unroll
    for (int a = 0; a < 4; ++a)
#pragma unroll
      for (int b = 0; b < 4; ++b) acc[a][b] = (f32x4){0.f,0.f,0.f,0.f};
#pragma unroll
    for (int ks = 0; ks < 8; ++ks) {
      short8 bf[4];
#pragma unroll
      for (int nf = 0; nf < 4; ++nf) {
        int off = (colbase + nf * 16 + li) * 256 + ks * 32 + g * 8;
        bf[nf] = WB ? *(const short8*)(wb + 2 * 65536 + off) : cvt8(Wkf + off);
      }
      short8 af[4];
#pragma unroll
      for (int mt = 0; mt < 4; ++mt)
        af[mt] = *(const short8*)&sX[(mt * 16 + li) * 264 + ks * 32 + g * 8];
#pragma unroll
      for (int nf = 0; nf < 4; ++nf)
#pragma unroll
        for (int mt = 0; mt < 4; ++mt)
          acc[mt][nf] = MFMA_BF16(af[mt], bf[nf], acc[mt][nf]);
    }
    float bkv[4];
#pragma unroll
    for (int nf = 0; nf < 4; ++nf) bkv[nf] = bk[colbase + nf * 16 + li];
#pragma unroll
    for (int nd = 0; nd < 2; ++nd)
#pragma unroll
      for (int t = 0; t < 2; ++t) {
        int mt = nd * 2 + t;
#pragma unroll
        for (int nf = 0; nf < 4; ++nf)
#pragma unroll
          for (int r = 0; r < 4; ++r)
            myS[(g * 4 + r) * 72 + nf * 16 + li] = f2bf(acc[mt][nf][r] + bkv[nf]);
#pragma unroll
        for (int k2 = 0; k2 < 2; ++k2)
          kbf[nd][t][k2] = *(const short8*)&myS[li * 72 + k2 * 32 + g * 8];
      }
  }
  // -------- phase 3a: QK^T + softmax + P (bf16 A-frags); frees qa/kbf
  short8 pa[2][2];
#pragma unroll
  for (int nd = 0; nd < 2; ++nd) {
    const int dgn = dg2[nd];
    f32x4 sc[2][2];
#pragma unroll
    for (int a = 0; a < 2; ++a)
#pragma unroll
      for (int b = 0; b < 2; ++b) sc[a][b] = (f32x4){0.f,0.f,0.f,0.f};
#pragma unroll
    for (int k2 = 0; k2 < 2; ++k2)
#pragma unroll
      for (int mt = 0; mt < 2; ++mt)
#pragma unroll
        for (int nt = 0; nt < 2; ++nt)
          sc[mt][nt] = MFMA_BF16(qa[nd][mt][k2], kbf[nd][nt][k2], sc[mt][nt]);
#pragma unroll
    for (int mt = 0; mt < 2; ++mt) {
#pragma unroll
      for (int nt = 0; nt < 2; ++nt) {
        bool ok = (nt * 16 + li) < dgn;
#pragma unroll
        for (int r = 0; r < 4; ++r) sc[mt][nt][r] = ok ? sc[mt][nt][r] : -1e30f;
      }
#pragma unroll
      for (int r = 0; r < 4; ++r) {
        float mx = fmaxf(sc[mt][0][r], sc[mt][1][r]);
#pragma unroll
        for (int d = 1; d < 16; d <<= 1) mx = fmaxf(mx, __shfl_xor(mx, d));
        float s0 = __expf(sc[mt][0][r] - mx);
        float s1 = __expf(sc[mt][1][r] - mx);
        float sum = s0 + s1;
#pragma unroll
        for (int d = 1; d < 16; d <<= 1) sum += __shfl_xor(sum, d);
        float inv = __builtin_amdgcn_rcpf(sum);
        sc[mt][0][r] = s0 * inv;
        sc[mt][1][r] = s1 * inv;
      }
    }
#pragma unroll
    for (int mt = 0; mt < 2; ++mt)
#pragma unroll
      for (int nt = 0; nt < 2; ++nt)
#pragma unroll
        for (int r = 0; r < 4; ++r)
          myS[(mt * 16 + g * 4 + r) * 36 + nt * 16 + li] = f2bf(sc[mt][nt][r]);
#pragma unroll
    for (int t = 0; t < 2; ++t)
      pa[nd][t] = *(const short8*)&myS[(t * 16 + li) * 36 + g * 8];
  }
  // -------- phase 3b: V GEMM (reads sX), then PV + attn-out
  {
    f32x4 acc[4][4];
#pragma unroll
    for (int a = 0; a < 4; ++a)
#pragma unroll
      for (int b = 0; b < 4; ++b) acc[a][b] = (f32x4){0.f,0.f,0.f,0.f};
#pragma unroll
    for (int ks = 0; ks < 8; ++ks) {
      short8 bf[4];
#pragma unroll
      for (int nf = 0; nf < 4; ++nf) {
        int off = (colbase + nf * 16 + li) * 256 + ks * 32 + g * 8;
        bf[nf] = WB ? *(const short8*)(wb + 3 * 65536 + off) : cvt8(Wvf + off);
      }
      short8 af[4];
#pragma unroll
      for (int mt = 0; mt < 4; ++mt)
        af[mt] = *(const short8*)&sX[(mt * 16 + li) * 264 + ks * 32 + g * 8];
#pragma unroll
      for (int nf = 0; nf < 4; ++nf)
#pragma unroll
        for (int mt = 0; mt < 4; ++mt)
          acc[mt][nf] = MFMA_BF16(af[mt], bf[nf], acc[mt][nf]);
    }
    __syncthreads();   // (4) all sX reads done -> attn-out may overlay
    float bvv[4];
#pragma unroll
    for (int nf = 0; nf < 4; ++nf) bvv[nf] = bv[colbase + nf * 16 + li];
#pragma unroll
    for (int nd = 0; nd < 2; ++nd) {
      short8 vbf[4];
#pragma unroll
      for (int c2 = 0; c2 < 2; ++c2) {   // V^T half-tile [32 cols][40 keys]
#pragma unroll
        for (int nh = 0; nh < 2; ++nh) {
          int nf = c2 * 2 + nh;
#pragma unroll
          for (int t = 0; t < 2; ++t) {
            int mt = nd * 2 + t;
#pragma unroll
            for (int r = 0; r < 4; ++r)
              myS[(nh * 16 + li) * 40 + t * 16 + g * 4 + r] = f2bf(acc[mt][nf][r] + bvv[nf]);
          }
        }
#pragma unroll
        for (int nh = 0; nh < 2; ++nh)
          vbf[c2 * 2 + nh] = *(const short8*)&myS[(nh * 16 + li) * 40 + g * 8];
      }
      f32x4 o[2][4];
#pragma unroll
      for (int a = 0; a < 2; ++a)
#pragma unroll
        for (int b = 0; b < 4; ++b) o[a][b] = (f32x4){0.f,0.f,0.f,0.f};
#pragma unroll
      for (int nf = 0; nf < 4; ++nf)
#pragma unroll
        for (int t = 0; t < 2; ++t) o[t][nf] = MFMA_BF16(pa[nd][t], vbf[nf], o[t][nf]);
#pragma unroll
      for (int t = 0; t < 2; ++t)
#pragma unroll
        for (int nf = 0; nf < 4; ++nf)
#pragma unroll
          for (int r = 0; r < 4; ++r)
            sX[((nd * 2 + t) * 16 + g * 4 + r) * 264 + colbase + nf * 16 + li] = f2bf(o[t][nf][r]);
    }
  }
  __syncthreads();   // (5) attn-out complete

  // -------- phase 4: Wo GEMM + gelu + per-node group softmax + scatter
  {
    f32x4 acc[4][4];
#pragma unroll
    for (int a = 0; a < 4; ++a)
#pragma unroll
      for (int b = 0; b < 4; ++b) acc[a][b] = (f32x4){0.f,0.f,0.f,0.f};
#pragma unroll
    for (int ks = 0; ks < 8; ++ks) {
      short8 bf[4];
#pragma unroll
      for (int nf = 0; nf < 4; ++nf) {
        int off = (colbase + nf * 16 + li) * 256 + ks * 32 + g * 8;
        bf[nf] = WB ? *(const short8*)(wb + 4 * 65536 + off) : cvt8(Wof + off);
      }
      short8 af[4];
#pragma unroll
      for (int mt = 0; mt < 4; ++mt)
        af[mt] = *(const short8*)&sX[(mt * 16 + li) * 264 + ks * 32 + g * 8];
#pragma unroll
      for (int nf = 0; nf < 4; ++nf)
#pragma unroll
        for (int mt = 0; mt < 4; ++mt)
          acc[mt][nf] = MFMA_BF16(af[mt], bf[nf], acc[mt][nf]);
    }
#pragma unroll
    for (int nf = 0; nf < 4; ++nf) {
      float b = bo[colbase + nf * 16 + li];
#pragma unroll
      for (int mt = 0; mt < 4; ++mt)
#pragma unroll
        for (int r = 0; r < 4; ++r) acc[mt][nf][r] = gelu_f(acc[mt][nf][r] + b);
    }
    float lp[4][4];
#pragma unroll
    for (int mt = 0; mt < 4; ++mt)
#pragma unroll
      for (int r = 0; r < 4; ++r) lp[mt][r] = acc[mt][2][r] + acc[mt][3][r];
#pragma unroll
    for (int d = 1; d < 16; d <<= 1)
#pragma unroll
      for (int mt = 0; mt < 4; ++mt)
#pragma unroll
        for (int r = 0; r < 4; ++r) lp[mt][r] += __shfl_xor(lp[mt][r], d);
#pragma unroll
    for (int nd = 0; nd < 2; ++nd) {
      const int dgn = dg2[nd], stn = st2[nd];
      float ml[2][4], mx = -1e30f;
#pragma unroll
      for (int mt2 = 0; mt2 < 2; ++mt2)
#pragma unroll
        for (int r = 0; r < 4; ++r) {
          int rin = mt2 * 16 + g * 4 + r;
          ml[mt2][r] = (rin < dgn) ? lp[nd * 2 + mt2][r] * (1.f / 32.f) : -1e30f;
          mx = fmaxf(mx, ml[mt2][r]);
        }
      mx = fmaxf(mx, __shfl_xor(mx, 16));
      mx = fmaxf(mx, __shfl_xor(mx, 32));
      float ee[2][4], ss = 0.f;
#pragma unroll
      for (int mt2 = 0; mt2 < 2; ++mt2)
#pragma unroll
        for (int r = 0; r < 4; ++r) {
          int rin = mt2 * 16 + g * 4 + r;
          ee[mt2][r] = (rin < dgn) ? __expf(ml[mt2][r] - mx) : 0.f;
          ss += ee[mt2][r];
        }
      ss += __shfl_xor(ss, 16);
      ss += __shfl_xor(ss, 32);
      float inv = __builtin_amdgcn_rcpf(ss);
#pragma unroll
      for (int mt2 = 0; mt2 < 2; ++mt2)
#pragma unroll
        for (int r = 0; r < 4; ++r) {
          int rin = mt2 * 16 + g * 4 + r;
          if (rin < dgn) {
            int eo = e1[stn + rin];
            float a = ee[mt2][r] * inv;
            atomicAdd(&dout[(size_t)eo * 128 + w * 32 + li],      acc[nd * 2 + mt2][0][r] * a);
            atomicAdd(&dout[(size_t)eo * 128 + w * 32 + 16 + li], acc[nd * 2 + mt2][1][r] * a);
          }
        }
    }
  }
}

// ---------------------------------------------------------------- launch
extern "C" void kernel_launch(void* const* d_in, const int* in_sizes, int n_in,
                              void* d_out, int out_size, void* d_ws, size_t ws_size,
                              hipStream_t stream) {
  (void)n_in;
  const float* x  = (const float*)d_in[0];
  const float* Wc = (const float*)d_in[1];
  const float* bc = (const float*)d_in[2];
  const float* Wq = (const float*)d_in[3];
  const float* bq = (const float*)d_in[4];
  const float* Wk = (const float*)d_in[5];
  const float* bk = (const float*)d_in[6];
  const float* Wv = (const float*)d_in[7];
  const float* bv = (const float*)d_in[8];
  const float* Wo = (const float*)d_in[9];
  const float* bo = (const float*)d_in[10];
  const int* e0  = (const int*)d_in[11];
  const int* e1  = (const int*)d_in[12];
  const int* pos = (const int*)d_in[13];
  const int m = in_sizes[11];
  const int n = in_sizes[0] / 128;

  const size_t WBYTES = (size_t)5 * 65536 * sizeof(ushort_t);   // 640 KB
  const bool use_wb = ws_size >= WBYTES + (size_t)n * 2 * sizeof(int);

  ushort_t* wb = (ushort_t*)d_ws;
  int* startp = use_wb ? (int*)((char*)d_ws + WBYTES) : (int*)d_ws;
  int* degp = startp + n;

  hipMemsetAsync(d_out, 0, (size_t)out_size * sizeof(float), stream);
  hipMemsetAsync(startp, 0, (size_t)n * 2 * sizeof(int), stream);

  k_prep<<<(m + 255) / 256, 256, 0, stream>>>(e0, pos, m, startp, degp);
  const int nb = (n + 1) / 2;
  if (use_wb) {
    k_wcvt<<<(5 * 65536 + 255) / 256, 256, 0, stream>>>(Wc, Wq, Wk, Wv, Wo, wb);
    k_fused5<true><<<nb, 256, 0, stream>>>(x, wb, Wc, bc, Wq, bq, Wk, bk, Wv, bv, Wo, bo,
                                           e1, startp, degp, (float*)d_out, n);
  } else {
    k_fused5<false><<<nb, 256, 0, stream>>>(x, nullptr, Wc, bc, Wq, bq, Wk, bk, Wv, bv, Wo, bo,
                                            e1, startp, degp, (float*)d_out, n);
  }
}